// Round 1
// baseline (207.018 us; speedup 1.0000x reference)
//
#include <hip/hip_runtime.h>

typedef short bshort8 __attribute__((ext_vector_type(8)));
typedef float f32x4 __attribute__((ext_vector_type(4)));

#define DEVFN static __device__ __forceinline__

DEVFN unsigned short f2bf(float f) {
    union { float f; unsigned u; } v; v.f = f;
    unsigned r = (v.u + 0x7FFFu + ((v.u >> 16) & 1u)) >> 16;
    return (unsigned short)r;
}

// XOR swizzle for 128-byte LDS rows (8 chunks of 16B)
DEVFN int swzf(int row) { return (row & 7) ^ ((row >> 3) & 7); }
// XOR swizzle for 64-byte LDS rows (4 chunks of 16B)
DEVFN int swzf2(int row) { return (row & 3) ^ ((row >> 2) & 3); }

#define GLDS16(g, l)                                                            \
    __builtin_amdgcn_global_load_lds(                                           \
        (__attribute__((address_space(1))) void*)(g),                           \
        (__attribute__((address_space(3))) void*)(l), 16, 0, 0)

// ---------------------------------------------------------------- prep kernels

__global__ void cast_x_kernel(const float* __restrict__ x,
                              unsigned short* __restrict__ xb, int n4) {
    int i = blockIdx.x * blockDim.x + threadIdx.x;
    int stride = gridDim.x * blockDim.x;
    for (; i < n4; i += stride) {
        float4 v = ((const float4*)x)[i];
        ushort4 o;
        o.x = f2bf(v.x); o.y = f2bf(v.y); o.z = f2bf(v.z); o.w = f2bf(v.w);
        ((ushort4*)xb)[i] = o;
    }
}

// src is K x N (f32, row-major). dst is N x K (bf16, row-major).
__global__ void transpose_cast_kernel(const float* __restrict__ src,
                                      unsigned short* __restrict__ dst,
                                      int K, int N) {
    __shared__ float tile[32][33];
    int n0 = blockIdx.x * 32, k0 = blockIdx.y * 32;
    int tx = threadIdx.x, ty = threadIdx.y; // (32, 8)
#pragma unroll
    for (int i = 0; i < 4; i++)
        tile[ty + i * 8][tx] = src[(size_t)(k0 + ty + i * 8) * N + n0 + tx];
    __syncthreads();
#pragma unroll
    for (int i = 0; i < 4; i++)
        dst[(size_t)(n0 + ty + i * 8) * K + k0 + tx] = f2bf(tile[tx][ty + i * 8]);
}

__global__ void rope_table_kernel(float2* __restrict__ cs) {
    int idx = blockIdx.x * 256 + threadIdx.x; // < 2048*32
    int t = idx >> 5, i = idx & 31;
    float inv_freq = powf(10000.0f, -(float)i / 32.0f);
    float a = (float)t * inv_freq;
    cs[idx] = make_float2(cosf(a), sinf(a));
}

// ------------------------------------------------------------- QKV GEMM + RoPE
// C = Xb(4096x1024) @ W(1024x1536) with W supplied transposed (wt: 1536x1024).
// n in [0,1024): Q (RoPE + 0.125 scale); [1024,1280): K (RoPE); [1280,1536): V.

__global__ __launch_bounds__(256) void gemm_qkv_kernel(
    const unsigned short* __restrict__ xb, const unsigned short* __restrict__ wt,
    const float2* __restrict__ cs, unsigned short* __restrict__ Qb,
    unsigned short* __restrict__ Kb, unsigned short* __restrict__ Vb) {
    __shared__ char smem[16384];
    char* As = smem;
    char* Bs = smem + 8192;
    const int tid = threadIdx.x;
    const int lane = tid & 63, w = tid >> 6;
    const int wm = w >> 1, wn = w & 1;
    const int m0 = blockIdx.y * 128, n0 = blockIdx.x * 128;
    const int l15 = lane & 15, g = lane >> 4;

    // staging geometry (64B rows, 4 chunks)
    const int srow = tid >> 2;
    const int sc0 = (tid & 3) ^ swzf2(srow);
    const int sc1 = (tid & 3) ^ swzf2(srow + 64);
    const unsigned short* aRow0 = xb + (size_t)(m0 + srow) * 1024 + sc0 * 8;
    const unsigned short* aRow1 = xb + (size_t)(m0 + srow + 64) * 1024 + sc1 * 8;
    const unsigned short* bRow0 = wt + (size_t)(n0 + srow) * 1024 + sc0 * 8;
    const unsigned short* bRow1 = wt + (size_t)(n0 + srow + 64) * 1024 + sc1 * 8;

    f32x4 acc[4][4] = {};
    for (int kt = 0; kt < 32; kt++) {
        __syncthreads();
        GLDS16(aRow0 + kt * 32, As + tid * 16);
        GLDS16(aRow1 + kt * 32, As + tid * 16 + 4096);
        GLDS16(bRow0 + kt * 32, Bs + tid * 16);
        GLDS16(bRow1 + kt * 32, Bs + tid * 16 + 4096);
        __syncthreads();
        bshort8 af[4], bf[4];
#pragma unroll
        for (int fm = 0; fm < 4; fm++) {
            int row = wm * 64 + fm * 16 + l15;
            af[fm] = *(const bshort8*)(As + row * 64 + ((g ^ swzf2(row)) << 4));
        }
#pragma unroll
        for (int fn = 0; fn < 4; fn++) {
            int row = wn * 64 + fn * 16 + l15;
            bf[fn] = *(const bshort8*)(Bs + row * 64 + ((g ^ swzf2(row)) << 4));
        }
#pragma unroll
        for (int fm = 0; fm < 4; fm++)
#pragma unroll
            for (int fn = 0; fn < 4; fn++)
                acc[fm][fn] = __builtin_amdgcn_mfma_f32_16x16x32_bf16(
                    af[fm], bf[fn], acc[fm][fn], 0, 0, 0);
    }

    const bool isV = (n0 >= 1280);
    const bool isK = (n0 >= 1024) && !isV;
#pragma unroll
    for (int fm = 0; fm < 4; fm++) {
#pragma unroll
        for (int r = 0; r < 4; r++) {
            int m = m0 + wm * 64 + fm * 16 + g * 4 + r;
            int b = m >> 11, t = m & 2047;
            if (isV) {
#pragma unroll
                for (int fn = 0; fn < 4; fn++) {
                    int n = n0 + wn * 64 + fn * 16 + l15;
                    int d = n & 63, vh = (n - 1280) >> 6;
                    Vb[((size_t)(b * 4 + vh) * 2048 + t) * 64 + d] =
                        f2bf(acc[fm][fn][r]);
                }
            } else {
                float2 c0 = cs[t * 32 + l15];
                float2 c1 = cs[t * 32 + 16 + l15];
#pragma unroll
                for (int fn = 0; fn < 4; fn++) {
                    int n = n0 + wn * 64 + fn * 16 + l15;
                    int d = n & 63;
                    float val = acc[fm][fn][r];
                    float pair = acc[fm][fn ^ 2][r];
                    float rot = (fn < 2) ? -pair : pair;
                    float2 cc = (fn & 1) ? c1 : c0;
                    float o = val * cc.x + rot * cc.y;
                    if (isK) {
                        int kh = (n - 1024) >> 6;
                        Kb[((size_t)(b * 4 + kh) * 2048 + t) * 64 + d] = f2bf(o);
                    } else {
                        o *= 0.125f;
                        int h = n >> 6;
                        Qb[((size_t)(b * 16 + h) * 2048 + t) * 64 + d] = f2bf(o);
                    }
                }
            }
        }
    }
}

// ------------------------------------------------------------- flash attention
// Block: 128 Q rows, 4 waves x 32 rows. KV tile = 64. Causal, GQA group 4.

__global__ __launch_bounds__(256) void attn_kernel(
    const unsigned short* __restrict__ Qb, const unsigned short* __restrict__ Kb,
    const unsigned short* __restrict__ Vb, unsigned short* __restrict__ Ob) {
    __shared__ char smem[32768];
    char* QP = smem;          // 16KB Q tile (128 rows x 128B); per-wave P reuses
    char* KS = smem + 16384;  // 8KB K tile (64 x 128B)
    char* VS = smem + 24576;  // 8KB V^T tile (64 d-rows x 128B)

    const int tid = threadIdx.x, lane = tid & 63, w = tid >> 6;
    const int l15 = lane & 15, g = lane >> 4;
    const int qt = blockIdx.x, h = blockIdx.y, b = blockIdx.z;
    const int kvh = h >> 2;
    const int qs = qt * 128;

    const unsigned short* Qbase = Qb + ((size_t)(b * 16 + h) * 2048 + qs) * 64;
    const unsigned short* Kbase = Kb + (size_t)(b * 4 + kvh) * 2048 * 64;
    const unsigned short* Vbase = Vb + (size_t)(b * 4 + kvh) * 2048 * 64;

    // stage Q (swizzled via pre-swizzled global source)
    {
        int row = tid >> 3, pc = tid & 7;
#pragma unroll
        for (int it = 0; it < 4; it++) {
            int r = row + it * 32;
            int lc = pc ^ swzf(r);
            GLDS16(Qbase + (size_t)r * 64 + lc * 8, QP + tid * 16 + it * 4096);
        }
    }
    __syncthreads();
    bshort8 qf[2][2];
#pragma unroll
    for (int fm = 0; fm < 2; fm++) {
        int row = w * 32 + fm * 16 + l15;
#pragma unroll
        for (int ks = 0; ks < 2; ks++) {
            int lc = ks * 4 + g;
            qf[fm][ks] = *(const bshort8*)(QP + row * 128 + ((lc ^ swzf(row)) << 4));
        }
    }

    f32x4 O[2][4] = {};
    float m_run[2][4], l_run[2][4];
#pragma unroll
    for (int fm = 0; fm < 2; fm++)
#pragma unroll
        for (int r = 0; r < 4; r++) { m_run[fm][r] = -1e30f; l_run[fm][r] = 0.f; }

    char* PB = QP + w * 4096;  // per-wave P tile (32 rows x 128B) = own Q strip
    const int ntiles = qs / 64 + 2;
    const int wave_last = (qs + w * 32 + 31) >> 6;

    for (int kt = 0; kt < ntiles; kt++) {
        const int kv0 = kt * 64;
        __syncthreads();
        // stage K
        {
            int row = tid >> 3, pc = tid & 7;
#pragma unroll
            for (int it = 0; it < 2; it++) {
                int r = row + it * 32;
                int lc = pc ^ swzf(r);
                GLDS16(Kbase + (size_t)(kv0 + r) * 64 + lc * 8,
                       KS + tid * 16 + it * 4096);
            }
        }
        // stage V transposed (register path, swizzled scalar writes)
        {
            int kvl = tid >> 2;
            int dbase = (tid & 3) * 16;
            const int4* vp = (const int4*)(Vbase + (size_t)(kv0 + kvl) * 64 + dbase);
            union { int4 v[2]; unsigned short s[16]; } vv;
            vv.v[0] = vp[0];
            vv.v[1] = vp[1];
            int cib = kvl * 2;
            int lowb = cib & 15, ch = cib >> 4;
#pragma unroll
            for (int j = 0; j < 16; j++) {
                int d = dbase + j;
                *(unsigned short*)(VS + d * 128 + ((ch ^ swzf(d)) << 4) + lowb) =
                    vv.s[j];
            }
        }
        __syncthreads();
        if (kt <= wave_last) {
            // S = Q K^T   (D: row=q via (g*4+r), col=kv via l15)
            bshort8 kf[4][2];
#pragma unroll
            for (int fn = 0; fn < 4; fn++) {
                int row = fn * 16 + l15;
#pragma unroll
                for (int ks = 0; ks < 2; ks++) {
                    int lc = ks * 4 + g;
                    kf[fn][ks] =
                        *(const bshort8*)(KS + row * 128 + ((lc ^ swzf(row)) << 4));
                }
            }
            f32x4 S[2][4];
#pragma unroll
            for (int fm = 0; fm < 2; fm++)
#pragma unroll
                for (int fn = 0; fn < 4; fn++) {
                    f32x4 a = {};
                    a = __builtin_amdgcn_mfma_f32_16x16x32_bf16(qf[fm][0], kf[fn][0], a, 0, 0, 0);
                    a = __builtin_amdgcn_mfma_f32_16x16x32_bf16(qf[fm][1], kf[fn][1], a, 0, 0, 0);
                    S[fm][fn] = a;
                }
            if (kv0 + 63 > qs + w * 32) {  // causal mask needed
#pragma unroll
                for (int fm = 0; fm < 2; fm++)
#pragma unroll
                    for (int r = 0; r < 4; r++) {
                        int q = qs + w * 32 + fm * 16 + g * 4 + r;
#pragma unroll
                        for (int fn = 0; fn < 4; fn++) {
                            int kv = kv0 + fn * 16 + l15;
                            if (kv > q) S[fm][fn][r] = -1e30f;
                        }
                    }
            }
            // online softmax (rows live in 16-lane groups)
#pragma unroll
            for (int fm = 0; fm < 2; fm++) {
#pragma unroll
                for (int r = 0; r < 4; r++) {
                    float mt = fmaxf(fmaxf(S[fm][0][r], S[fm][1][r]),
                                     fmaxf(S[fm][2][r], S[fm][3][r]));
#pragma unroll
                    for (int off = 1; off < 16; off <<= 1)
                        mt = fmaxf(mt, __shfl_xor(mt, off));
                    float mn = fmaxf(m_run[fm][r], mt);
                    float alpha = __expf(m_run[fm][r] - mn);
                    m_run[fm][r] = mn;
                    float rs = 0.f;
                    int qlocal = fm * 16 + g * 4 + r;
                    int swq = swzf(qlocal);
#pragma unroll
                    for (int fn = 0; fn < 4; fn++) {
                        float p = __expf(S[fm][fn][r] - mn);
                        rs += p;
                        int cib = (fn * 16 + l15) * 2;
                        *(unsigned short*)(PB + qlocal * 128 +
                                           (((cib >> 4) ^ swq) << 4) + (cib & 15)) =
                            f2bf(p);
                    }
#pragma unroll
                    for (int off = 1; off < 16; off <<= 1) rs += __shfl_xor(rs, off);
                    l_run[fm][r] = l_run[fm][r] * alpha + rs;
#pragma unroll
                    for (int fd = 0; fd < 4; fd++) O[fm][fd][r] *= alpha;
                }
            }
            asm volatile("s_waitcnt lgkmcnt(0)" ::: "memory");
            __builtin_amdgcn_sched_barrier(0);
            // PV: O += P @ V
            bshort8 pf[2][2], vf[4][2];
#pragma unroll
            for (int fm = 0; fm < 2; fm++) {
                int row = fm * 16 + l15;
#pragma unroll
                for (int ks = 0; ks < 2; ks++) {
                    int lc = ks * 4 + g;
                    pf[fm][ks] =
                        *(const bshort8*)(PB + row * 128 + ((lc ^ swzf(row)) << 4));
                }
            }
#pragma unroll
            for (int fd = 0; fd < 4; fd++) {
                int row = fd * 16 + l15;
#pragma unroll
                for (int ks = 0; ks < 2; ks++) {
                    int lc = ks * 4 + g;
                    vf[fd][ks] =
                        *(const bshort8*)(VS + row * 128 + ((lc ^ swzf(row)) << 4));
                }
            }
#pragma unroll
            for (int fm = 0; fm < 2; fm++)
#pragma unroll
                for (int fd = 0; fd < 4; fd++) {
                    O[fm][fd] = __builtin_amdgcn_mfma_f32_16x16x32_bf16(
                        pf[fm][0], vf[fd][0], O[fm][fd], 0, 0, 0);
                    O[fm][fd] = __builtin_amdgcn_mfma_f32_16x16x32_bf16(
                        pf[fm][1], vf[fd][1], O[fm][fd], 0, 0, 0);
                }
        }
    }
    // write attention output: [b*2048+t][h*64+d] bf16
#pragma unroll
    for (int fm = 0; fm < 2; fm++)
#pragma unroll
        for (int r = 0; r < 4; r++) {
            int t = qs + w * 32 + fm * 16 + g * 4 + r;
            float inv = 1.0f / l_run[fm][r];
            size_t rowoff = (size_t)(b * 2048 + t) * 1024 + h * 64;
#pragma unroll
            for (int fd = 0; fd < 4; fd++)
                Ob[rowoff + fd * 16 + l15] = f2bf(O[fm][fd][r] * inv);
        }
}

// ------------------------------------------------------------- output GEMM
__global__ __launch_bounds__(256) void gemm_out_kernel(
    const unsigned short* __restrict__ ab, const unsigned short* __restrict__ wot,
    float* __restrict__ out) {
    __shared__ char smem[16384];
    char* As = smem;
    char* Bs = smem + 8192;
    const int tid = threadIdx.x;
    const int lane = tid & 63, w = tid >> 6;
    const int wm = w >> 1, wn = w & 1;
    const int m0 = blockIdx.y * 128, n0 = blockIdx.x * 128;
    const int l15 = lane & 15, g = lane >> 4;

    const int srow = tid >> 2;
    const int sc0 = (tid & 3) ^ swzf2(srow);
    const int sc1 = (tid & 3) ^ swzf2(srow + 64);
    const unsigned short* aRow0 = ab + (size_t)(m0 + srow) * 1024 + sc0 * 8;
    const unsigned short* aRow1 = ab + (size_t)(m0 + srow + 64) * 1024 + sc1 * 8;
    const unsigned short* bRow0 = wot + (size_t)(n0 + srow) * 1024 + sc0 * 8;
    const unsigned short* bRow1 = wot + (size_t)(n0 + srow + 64) * 1024 + sc1 * 8;

    f32x4 acc[4][4] = {};
    for (int kt = 0; kt < 32; kt++) {
        __syncthreads();
        GLDS16(aRow0 + kt * 32, As + tid * 16);
        GLDS16(aRow1 + kt * 32, As + tid * 16 + 4096);
        GLDS16(bRow0 + kt * 32, Bs + tid * 16);
        GLDS16(bRow1 + kt * 32, Bs + tid * 16 + 4096);
        __syncthreads();
        bshort8 af[4], bf[4];
#pragma unroll
        for (int fm = 0; fm < 4; fm++) {
            int row = wm * 64 + fm * 16 + l15;
            af[fm] = *(const bshort8*)(As + row * 64 + ((g ^ swzf2(row)) << 4));
        }
#pragma unroll
        for (int fn = 0; fn < 4; fn++) {
            int row = wn * 64 + fn * 16 + l15;
            bf[fn] = *(const bshort8*)(Bs + row * 64 + ((g ^ swzf2(row)) << 4));
        }
#pragma unroll
        for (int fm = 0; fm < 4; fm++)
#pragma unroll
            for (int fn = 0; fn < 4; fn++)
                acc[fm][fn] = __builtin_amdgcn_mfma_f32_16x16x32_bf16(
                    af[fm], bf[fn], acc[fm][fn], 0, 0, 0);
    }
#pragma unroll
    for (int fm = 0; fm < 4; fm++)
#pragma unroll
        for (int r = 0; r < 4; r++) {
            int m = m0 + wm * 64 + fm * 16 + g * 4 + r;
#pragma unroll
            for (int fn = 0; fn < 4; fn++) {
                int n = n0 + wn * 64 + fn * 16 + l15;
                out[(size_t)m * 1024 + n] = acc[fm][fn][r];
            }
        }
}

// ---------------------------------------------------------------- launch

extern "C" void kernel_launch(void* const* d_in, const int* in_sizes, int n_in,
                              void* d_out, int out_size, void* d_ws, size_t ws_size,
                              hipStream_t stream) {
    const float* x = (const float*)d_in[0];
    const float* wq = (const float*)d_in[1];
    const float* wk = (const float*)d_in[2];
    const float* wv = (const float*)d_in[3];
    const float* wo = (const float*)d_in[4];
    float* out = (float*)d_out;
    char* ws = (char*)d_ws;

    unsigned short* xb = (unsigned short*)(ws);                  // 8 MB
    unsigned short* wt = (unsigned short*)(ws + 8388608);        // 3 MB (1536x1024)
    unsigned short* wot = (unsigned short*)(ws + 11534336);      // 2 MB
    float2* cs = (float2*)(ws + 13631488);                       // 512 KB
    unsigned short* Qb = (unsigned short*)(ws + 14155776);       // 8 MB
    unsigned short* Kb = (unsigned short*)(ws + 22544384);       // 2 MB
    unsigned short* Vb = (unsigned short*)(ws + 24641536);       // 2 MB
    unsigned short* Ob = (unsigned short*)(ws + 26738688);       // 8 MB

    hipLaunchKernelGGL(cast_x_kernel, dim3(2048), dim3(256), 0, stream, x, xb,
                       4194304 / 4);
    hipLaunchKernelGGL(transpose_cast_kernel, dim3(32, 32), dim3(32, 8), 0, stream,
                       wq, wt, 1024, 1024);
    hipLaunchKernelGGL(transpose_cast_kernel, dim3(8, 32), dim3(32, 8), 0, stream,
                       wk, wt + 1024 * 1024, 1024, 256);
    hipLaunchKernelGGL(transpose_cast_kernel, dim3(8, 32), dim3(32, 8), 0, stream,
                       wv, wt + 1280 * 1024, 1024, 256);
    hipLaunchKernelGGL(transpose_cast_kernel, dim3(32, 32), dim3(32, 8), 0, stream,
                       wo, wot, 1024, 1024);
    hipLaunchKernelGGL(rope_table_kernel, dim3(256), dim3(256), 0, stream, cs);
    hipLaunchKernelGGL(gemm_qkv_kernel, dim3(12, 32), dim3(256), 0, stream, xb, wt,
                       cs, Qb, Kb, Vb);
    hipLaunchKernelGGL(attn_kernel, dim3(16, 16, 2), dim3(256), 0, stream, Qb, Kb,
                       Vb, Ob);
    hipLaunchKernelGGL(gemm_out_kernel, dim3(8, 32), dim3(256), 0, stream, Ob, wot,
                       out);
}

// Round 2
// 137.611 us; speedup vs baseline: 1.5044x; 1.5044x over previous
//
#include <hip/hip_runtime.h>

typedef short bshort8 __attribute__((ext_vector_type(8)));
typedef float f32x4 __attribute__((ext_vector_type(4)));

#define DEVFN static __device__ __forceinline__

DEVFN unsigned short f2bf(float f) {
    union { float f; unsigned u; } v; v.f = f;
    unsigned r = (v.u + 0x7FFFu + ((v.u >> 16) & 1u)) >> 16;
    return (unsigned short)r;
}

// XOR swizzle for 128-byte LDS rows (8 chunks of 16B)
DEVFN int swzf(int row) { return (row & 7) ^ ((row >> 3) & 7); }
// XOR swizzle for 64-byte LDS rows (4 chunks of 16B)
DEVFN int swzf2(int row) { return (row & 3) ^ ((row >> 2) & 3); }

#define GLDS16(g, l)                                                            \
    __builtin_amdgcn_global_load_lds(                                           \
        (__attribute__((address_space(1))) void*)(g),                           \
        (__attribute__((address_space(3))) void*)(l), 16, 0, 0)

// ---------------------------------------------------------------- prep kernels

__global__ void cast_x_kernel(const float* __restrict__ x,
                              unsigned short* __restrict__ xb, int n4) {
    int i = blockIdx.x * blockDim.x + threadIdx.x;
    int stride = gridDim.x * blockDim.x;
    for (; i < n4; i += stride) {
        float4 v = ((const float4*)x)[i];
        ushort4 o;
        o.x = f2bf(v.x); o.y = f2bf(v.y); o.z = f2bf(v.z); o.w = f2bf(v.w);
        ((ushort4*)xb)[i] = o;
    }
}

// src is K x N (f32, row-major). dst is N x K (bf16, row-major).
__global__ void transpose_cast_kernel(const float* __restrict__ src,
                                      unsigned short* __restrict__ dst,
                                      int K, int N) {
    __shared__ float tile[32][33];
    int n0 = blockIdx.x * 32, k0 = blockIdx.y * 32;
    int tx = threadIdx.x, ty = threadIdx.y; // (32, 8)
#pragma unroll
    for (int i = 0; i < 4; i++)
        tile[ty + i * 8][tx] = src[(size_t)(k0 + ty + i * 8) * N + n0 + tx];
    __syncthreads();
#pragma unroll
    for (int i = 0; i < 4; i++)
        dst[(size_t)(n0 + ty + i * 8) * K + k0 + tx] = f2bf(tile[tx][ty + i * 8]);
}

__global__ void rope_table_kernel(float2* __restrict__ cs) {
    int idx = blockIdx.x * 256 + threadIdx.x; // < 2048*32
    int t = idx >> 5, i = idx & 31;
    float inv_freq = powf(10000.0f, -(float)i / 32.0f);
    float a = (float)t * inv_freq;
    cs[idx] = make_float2(cosf(a), sinf(a));
}

// Vb[m][t][d] (2048x64) -> Vt[m][d][t] (64x2048), m = b*4+kvh
__global__ void transpose_v_kernel(const unsigned short* __restrict__ Vb,
                                   unsigned short* __restrict__ Vt) {
    __shared__ unsigned short tile[64][66];
    int t0 = blockIdx.x * 64, m = blockIdx.y;
    int tx = threadIdx.x, ty = threadIdx.y; // (32, 8)
    const unsigned short* src = Vb + (size_t)m * 2048 * 64;
    unsigned short* dst = Vt + (size_t)m * 64 * 2048;
#pragma unroll
    for (int i = 0; i < 8; i++) {
        int t = ty + i * 8;
        *(ushort2*)&tile[t][tx * 2] =
            *(const ushort2*)(src + (size_t)(t0 + t) * 64 + tx * 2);
    }
    __syncthreads();
#pragma unroll
    for (int i = 0; i < 8; i++) {
        int d = ty + i * 8;
        ushort2 o;
        o.x = tile[tx * 2][d];
        o.y = tile[tx * 2 + 1][d];
        *(ushort2*)(dst + (size_t)d * 2048 + t0 + tx * 2) = o;
    }
}

// ------------------------------------------------------------- QKV GEMM + RoPE
// C = Xb(4096x1024) @ W(1024x1536) with W supplied transposed (wt: 1536x1024).
// n in [0,1024): Q (RoPE + 0.125 scale); [1024,1280): K (RoPE); [1280,1536): V.

__global__ __launch_bounds__(256) void gemm_qkv_kernel(
    const unsigned short* __restrict__ xb, const unsigned short* __restrict__ wt,
    const float2* __restrict__ cs, unsigned short* __restrict__ Qb,
    unsigned short* __restrict__ Kb, unsigned short* __restrict__ Vb) {
    __shared__ char smem[16384];
    char* As = smem;
    char* Bs = smem + 8192;
    const int tid = threadIdx.x;
    const int lane = tid & 63, w = tid >> 6;
    const int wm = w >> 1, wn = w & 1;
    const int m0 = blockIdx.y * 128, n0 = blockIdx.x * 128;
    const int l15 = lane & 15, g = lane >> 4;

    const int srow = tid >> 2;
    const int sc0 = (tid & 3) ^ swzf2(srow);
    const int sc1 = (tid & 3) ^ swzf2(srow + 64);
    const unsigned short* aRow0 = xb + (size_t)(m0 + srow) * 1024 + sc0 * 8;
    const unsigned short* aRow1 = xb + (size_t)(m0 + srow + 64) * 1024 + sc1 * 8;
    const unsigned short* bRow0 = wt + (size_t)(n0 + srow) * 1024 + sc0 * 8;
    const unsigned short* bRow1 = wt + (size_t)(n0 + srow + 64) * 1024 + sc1 * 8;

    f32x4 acc[4][4] = {};
    for (int kt = 0; kt < 32; kt++) {
        __syncthreads();
        GLDS16(aRow0 + kt * 32, As + tid * 16);
        GLDS16(aRow1 + kt * 32, As + tid * 16 + 4096);
        GLDS16(bRow0 + kt * 32, Bs + tid * 16);
        GLDS16(bRow1 + kt * 32, Bs + tid * 16 + 4096);
        __syncthreads();
        bshort8 af[4], bf[4];
#pragma unroll
        for (int fm = 0; fm < 4; fm++) {
            int row = wm * 64 + fm * 16 + l15;
            af[fm] = *(const bshort8*)(As + row * 64 + ((g ^ swzf2(row)) << 4));
        }
#pragma unroll
        for (int fn = 0; fn < 4; fn++) {
            int row = wn * 64 + fn * 16 + l15;
            bf[fn] = *(const bshort8*)(Bs + row * 64 + ((g ^ swzf2(row)) << 4));
        }
#pragma unroll
        for (int fm = 0; fm < 4; fm++)
#pragma unroll
            for (int fn = 0; fn < 4; fn++)
                acc[fm][fn] = __builtin_amdgcn_mfma_f32_16x16x32_bf16(
                    af[fm], bf[fn], acc[fm][fn], 0, 0, 0);
    }

    const bool isV = (n0 >= 1280);
    const bool isK = (n0 >= 1024) && !isV;
#pragma unroll
    for (int fm = 0; fm < 4; fm++) {
#pragma unroll
        for (int r = 0; r < 4; r++) {
            int m = m0 + wm * 64 + fm * 16 + g * 4 + r;
            int b = m >> 11, t = m & 2047;
            if (isV) {
#pragma unroll
                for (int fn = 0; fn < 4; fn++) {
                    int n = n0 + wn * 64 + fn * 16 + l15;
                    int d = n & 63, vh = (n - 1280) >> 6;
                    Vb[((size_t)(b * 4 + vh) * 2048 + t) * 64 + d] =
                        f2bf(acc[fm][fn][r]);
                }
            } else {
                float2 c0 = cs[t * 32 + l15];
                float2 c1 = cs[t * 32 + 16 + l15];
#pragma unroll
                for (int fn = 0; fn < 4; fn++) {
                    int n = n0 + wn * 64 + fn * 16 + l15;
                    int d = n & 63;
                    float val = acc[fm][fn][r];
                    float pair = acc[fm][fn ^ 2][r];
                    float rot = (fn < 2) ? -pair : pair;
                    float2 cc = (fn & 1) ? c1 : c0;
                    float o = val * cc.x + rot * cc.y;
                    if (isK) {
                        int kh = (n - 1024) >> 6;
                        Kb[((size_t)(b * 4 + kh) * 2048 + t) * 64 + d] = f2bf(o);
                    } else {
                        o *= 0.125f;
                        int h = n >> 6;
                        Qb[((size_t)(b * 16 + h) * 2048 + t) * 64 + d] = f2bf(o);
                    }
                }
            }
        }
    }
}

// ------------------------------------------------------------- flash attention
// Swapped-QK^T layout. QBLK=64, 4 waves x 16 q-rows. KV tile 64, double-buffered.
// Each block runs two passes: qt = bx and qt = 31-bx (balanced causal work).

__global__ __launch_bounds__(256) void attn_kernel(
    const unsigned short* __restrict__ Qb, const unsigned short* __restrict__ Kb,
    const unsigned short* __restrict__ Vt, unsigned short* __restrict__ Ob) {
    __shared__ char smem[40960];
    char* QP = smem;  // 8KB: Q tile (64 x 128B); per-wave P/O-transpose reuses
    const int tid = threadIdx.x, lane = tid & 63, w = tid >> 6;
    const int l15 = lane & 15, g = lane >> 4;
    const int bx = blockIdx.x, h = blockIdx.y, b = blockIdx.z;
    const int kvh = h >> 2;
    const unsigned short* Kbase = Kb + (size_t)(b * 4 + kvh) * 2048 * 64;
    const unsigned short* Vbase = Vt + (size_t)(b * 4 + kvh) * 64 * 2048;
    const unsigned short* Qhead = Qb + (size_t)(b * 16 + h) * 2048 * 64;
    char* PB = QP + w * 2048;  // per-wave 16 rows x 128B

    const int srow8 = lane >> 3;  // 0..7
    const int sci = lane & 7;     // chunk 0..7

    for (int pass = 0; pass < 2; pass++) {
        const int qt = pass ? (31 - bx) : bx;
        const int qs = qt * 64;
        // stage Q (each wave its own 16 rows)
#pragma unroll
        for (int it = 0; it < 2; it++) {
            int row = w * 16 + it * 8 + srow8;
            int lc = sci ^ swzf(row);
            GLDS16(Qhead + (size_t)(qs + row) * 64 + lc * 8,
                   QP + w * 2048 + it * 1024 + lane * 16);
        }
        // stage K/V tile 0 into buffer 0
#pragma unroll
        for (int it = 0; it < 2; it++) {
            int row = w * 16 + it * 8 + srow8;
            int lc = sci ^ swzf(row);
            GLDS16(Kbase + (size_t)row * 64 + lc * 8,
                   smem + 8192 + w * 2048 + it * 1024 + lane * 16);
            GLDS16(Vbase + (size_t)row * 2048 + lc * 8,
                   smem + 24576 + w * 2048 + it * 1024 + lane * 16);
        }
        __syncthreads();
        const int qrow = w * 16 + l15;
        bshort8 qf[2];
#pragma unroll
        for (int ks = 0; ks < 2; ks++)
            qf[ks] = *(const bshort8*)(QP + qrow * 128 +
                                       (((ks * 4 + g) ^ swzf(qrow)) << 4));

        float m_run = -1e30f, l_run = 0.f;
        f32x4 O[4] = {};
        const int swq = swzf(l15);

        for (int kt = 0; kt <= qt; kt++) {
            char* KS = smem + 8192 + (kt & 1) * 8192;
            char* VS = smem + 24576 + (kt & 1) * 8192;
            if (kt < qt) {  // prefetch next K/V tile
                int kv0n = (kt + 1) * 64;
                char* KSn = smem + 8192 + ((kt + 1) & 1) * 8192;
                char* VSn = smem + 24576 + ((kt + 1) & 1) * 8192;
#pragma unroll
                for (int it = 0; it < 2; it++) {
                    int row = w * 16 + it * 8 + srow8;
                    int lc = sci ^ swzf(row);
                    GLDS16(Kbase + (size_t)(kv0n + row) * 64 + lc * 8,
                           KSn + w * 2048 + it * 1024 + lane * 16);
                    GLDS16(Vbase + (size_t)row * 2048 + kv0n + lc * 8,
                           VSn + w * 2048 + it * 1024 + lane * 16);
                }
            }
            // S^T[kv][q] = mfma(K, Q): row = kv (g*4+r), col = q (l15)
            f32x4 S[4];
#pragma unroll
            for (int fn = 0; fn < 4; fn++) {
                int row = fn * 16 + l15;
                bshort8 k0 = *(const bshort8*)(KS + row * 128 +
                                               ((g ^ swzf(row)) << 4));
                bshort8 k1 = *(const bshort8*)(KS + row * 128 +
                                               (((4 + g) ^ swzf(row)) << 4));
                f32x4 a = {};
                a = __builtin_amdgcn_mfma_f32_16x16x32_bf16(k0, qf[0], a, 0, 0, 0);
                a = __builtin_amdgcn_mfma_f32_16x16x32_bf16(k1, qf[1], a, 0, 0, 0);
                S[fn] = a;
            }
            if (kt == qt) {  // causal mask on the diagonal tile
                int qlocal = w * 16 + l15;
#pragma unroll
                for (int fn = 0; fn < 4; fn++)
#pragma unroll
                    for (int r = 0; r < 4; r++)
                        if (fn * 16 + g * 4 + r > qlocal) S[fn][r] = -1e30f;
            }
            // online softmax: row q = l15 spread over 4 g-groups
            float mt = -1e30f;
#pragma unroll
            for (int fn = 0; fn < 4; fn++)
#pragma unroll
                for (int r = 0; r < 4; r++) mt = fmaxf(mt, S[fn][r]);
            mt = fmaxf(mt, __shfl_xor(mt, 16));
            mt = fmaxf(mt, __shfl_xor(mt, 32));
            float mn = fmaxf(m_run, mt);
            float alpha = __expf(m_run - mn);
            m_run = mn;
            float rs = 0.f;
            float p[4][4];
#pragma unroll
            for (int fn = 0; fn < 4; fn++)
#pragma unroll
                for (int r = 0; r < 4; r++) {
                    p[fn][r] = __expf(S[fn][r] - mn);
                    rs += p[fn][r];
                }
            rs += __shfl_xor(rs, 16);
            rs += __shfl_xor(rs, 32);
            l_run = l_run * alpha + rs;
#pragma unroll
            for (int fd = 0; fd < 4; fd++) O[fd] *= alpha;
            // P -> LDS (packed bf16 pairs, 8 dword writes)
#pragma unroll
            for (int fn = 0; fn < 4; fn++)
#pragma unroll
                for (int w2 = 0; w2 < 2; w2++) {
                    unsigned word = (unsigned)f2bf(p[fn][2 * w2]) |
                                    ((unsigned)f2bf(p[fn][2 * w2 + 1]) << 16);
                    int byte = fn * 32 + g * 8 + w2 * 4;
                    *(unsigned*)(PB + l15 * 128 + (((byte >> 4) ^ swq) << 4) +
                                 (byte & 15)) = word;
                }
            asm volatile("s_waitcnt lgkmcnt(0)" ::: "memory");
            __builtin_amdgcn_sched_barrier(0);
            bshort8 pf[2];
#pragma unroll
            for (int ks = 0; ks < 2; ks++)
                pf[ks] = *(const bshort8*)(PB + l15 * 128 +
                                           (((ks * 4 + g) ^ swq) << 4));
            // O^T[d][q] += mfma(V^T, P)
#pragma unroll
            for (int fd = 0; fd < 4; fd++) {
                int row = fd * 16 + l15;
                bshort8 v0 = *(const bshort8*)(VS + row * 128 +
                                               ((g ^ swzf(row)) << 4));
                bshort8 v1 = *(const bshort8*)(VS + row * 128 +
                                               (((4 + g) ^ swzf(row)) << 4));
                O[fd] = __builtin_amdgcn_mfma_f32_16x16x32_bf16(v0, pf[0], O[fd], 0, 0, 0);
                O[fd] = __builtin_amdgcn_mfma_f32_16x16x32_bf16(v1, pf[1], O[fd], 0, 0, 0);
            }
            __syncthreads();
        }
        // epilogue: normalize, transpose through per-wave LDS, coalesced store
        float inv = 1.0f / l_run;
#pragma unroll
        for (int fd = 0; fd < 4; fd++)
#pragma unroll
            for (int w2 = 0; w2 < 2; w2++) {
                unsigned word = (unsigned)f2bf(O[fd][2 * w2] * inv) |
                                ((unsigned)f2bf(O[fd][2 * w2 + 1] * inv) << 16);
                int byte = fd * 32 + g * 8 + w2 * 4;
                *(unsigned*)(PB + l15 * 128 + (((byte >> 4) ^ swq) << 4) +
                             (byte & 15)) = word;
            }
        asm volatile("s_waitcnt lgkmcnt(0)" ::: "memory");
        __builtin_amdgcn_sched_barrier(0);
#pragma unroll
        for (int it = 0; it < 2; it++) {
            int r16 = it * 8 + srow8;
            int4 vv = *(const int4*)(PB + r16 * 128 + ((sci ^ swzf(r16)) << 4));
            int t = qs + w * 16 + r16;
            *(int4*)(Ob + (size_t)(b * 2048 + t) * 1024 + h * 64 + sci * 8) = vv;
        }
        __syncthreads();  // protect LDS before next pass restages
    }
}

// ------------------------------------------------------------- output GEMM
__global__ __launch_bounds__(256) void gemm_out_kernel(
    const unsigned short* __restrict__ ab, const unsigned short* __restrict__ wot,
    float* __restrict__ out) {
    __shared__ char smem[16384];
    char* As = smem;
    char* Bs = smem + 8192;
    const int tid = threadIdx.x;
    const int lane = tid & 63, w = tid >> 6;
    const int wm = w >> 1, wn = w & 1;
    const int m0 = blockIdx.y * 128, n0 = blockIdx.x * 128;
    const int l15 = lane & 15, g = lane >> 4;

    const int srow = tid >> 2;
    const int sc0 = (tid & 3) ^ swzf2(srow);
    const int sc1 = (tid & 3) ^ swzf2(srow + 64);
    const unsigned short* aRow0 = ab + (size_t)(m0 + srow) * 1024 + sc0 * 8;
    const unsigned short* aRow1 = ab + (size_t)(m0 + srow + 64) * 1024 + sc1 * 8;
    const unsigned short* bRow0 = wot + (size_t)(n0 + srow) * 1024 + sc0 * 8;
    const unsigned short* bRow1 = wot + (size_t)(n0 + srow + 64) * 1024 + sc1 * 8;

    f32x4 acc[4][4] = {};
    for (int kt = 0; kt < 32; kt++) {
        __syncthreads();
        GLDS16(aRow0 + kt * 32, As + tid * 16);
        GLDS16(aRow1 + kt * 32, As + tid * 16 + 4096);
        GLDS16(bRow0 + kt * 32, Bs + tid * 16);
        GLDS16(bRow1 + kt * 32, Bs + tid * 16 + 4096);
        __syncthreads();
        bshort8 af[4], bf[4];
#pragma unroll
        for (int fm = 0; fm < 4; fm++) {
            int row = wm * 64 + fm * 16 + l15;
            af[fm] = *(const bshort8*)(As + row * 64 + ((g ^ swzf2(row)) << 4));
        }
#pragma unroll
        for (int fn = 0; fn < 4; fn++) {
            int row = wn * 64 + fn * 16 + l15;
            bf[fn] = *(const bshort8*)(Bs + row * 64 + ((g ^ swzf2(row)) << 4));
        }
#pragma unroll
        for (int fm = 0; fm < 4; fm++)
#pragma unroll
            for (int fn = 0; fn < 4; fn++)
                acc[fm][fn] = __builtin_amdgcn_mfma_f32_16x16x32_bf16(
                    af[fm], bf[fn], acc[fm][fn], 0, 0, 0);
    }
#pragma unroll
    for (int fm = 0; fm < 4; fm++)
#pragma unroll
        for (int r = 0; r < 4; r++) {
            int m = m0 + wm * 64 + fm * 16 + g * 4 + r;
#pragma unroll
            for (int fn = 0; fn < 4; fn++) {
                int n = n0 + wn * 64 + fn * 16 + l15;
                out[(size_t)m * 1024 + n] = acc[fm][fn][r];
            }
        }
}

// ---------------------------------------------------------------- launch

extern "C" void kernel_launch(void* const* d_in, const int* in_sizes, int n_in,
                              void* d_out, int out_size, void* d_ws, size_t ws_size,
                              hipStream_t stream) {
    const float* x = (const float*)d_in[0];
    const float* wq = (const float*)d_in[1];
    const float* wk = (const float*)d_in[2];
    const float* wv = (const float*)d_in[3];
    const float* wo = (const float*)d_in[4];
    float* out = (float*)d_out;
    char* ws = (char*)d_ws;

    unsigned short* xb = (unsigned short*)(ws);                  // 8 MB
    unsigned short* wt = (unsigned short*)(ws + 8388608);        // 3 MB (1536x1024)
    unsigned short* Vtr = (unsigned short*)(ws + 8388608);       // 2 MB (reuses wt after gemm_qkv)
    unsigned short* wot = (unsigned short*)(ws + 11534336);      // 2 MB
    float2* cs = (float2*)(ws + 13631488);                       // 512 KB
    unsigned short* Qb = (unsigned short*)(ws + 14155776);       // 8 MB
    unsigned short* Kb = (unsigned short*)(ws + 22544384);       // 2 MB
    unsigned short* Vb = (unsigned short*)(ws + 24641536);       // 2 MB
    unsigned short* Ob = (unsigned short*)(ws + 26738688);       // 8 MB

    hipLaunchKernelGGL(cast_x_kernel, dim3(2048), dim3(256), 0, stream, x, xb,
                       4194304 / 4);
    hipLaunchKernelGGL(transpose_cast_kernel, dim3(32, 32), dim3(32, 8), 0, stream,
                       wq, wt, 1024, 1024);
    hipLaunchKernelGGL(transpose_cast_kernel, dim3(8, 32), dim3(32, 8), 0, stream,
                       wk, wt + 1024 * 1024, 1024, 256);
    hipLaunchKernelGGL(transpose_cast_kernel, dim3(8, 32), dim3(32, 8), 0, stream,
                       wv, wt + 1280 * 1024, 1024, 256);
    hipLaunchKernelGGL(transpose_cast_kernel, dim3(32, 32), dim3(32, 8), 0, stream,
                       wo, wot, 1024, 1024);
    hipLaunchKernelGGL(rope_table_kernel, dim3(256), dim3(256), 0, stream, cs);
    hipLaunchKernelGGL(gemm_qkv_kernel, dim3(12, 32), dim3(256), 0, stream, xb, wt,
                       cs, Qb, Kb, Vb);
    hipLaunchKernelGGL(transpose_v_kernel, dim3(32, 8), dim3(32, 8), 0, stream, Vb,
                       Vtr);
    hipLaunchKernelGGL(attn_kernel, dim3(16, 16, 2), dim3(256), 0, stream, Qb, Kb,
                       Vtr, Ob);
    hipLaunchKernelGGL(gemm_out_kernel, dim3(8, 32), dim3(256), 0, stream, Ob, wot,
                       out);
}